// Round 3
// baseline (1140.746 us; speedup 1.0000x reference)
//
#include <hip/hip_runtime.h>
#include <hip/hip_bf16.h>
#include <math.h>

#define N_TOK 32768
#define C_DIM 256
#define F_DIM 1024
#define E_NUM 16
#define TILE_R 128
#define NCH 16

typedef unsigned short u16;
typedef unsigned int u32;
typedef __attribute__((ext_vector_type(4))) u16 u16x4;
typedef __attribute__((ext_vector_type(8))) u16 u16x8;
typedef __attribute__((ext_vector_type(8))) short bf16x8;
typedef __attribute__((ext_vector_type(4))) u32 u32x4;
typedef __attribute__((ext_vector_type(4))) float f32x4;
typedef __attribute__((ext_vector_type(16))) float f32x16;

#define AS1 __attribute__((address_space(1)))
#define AS3 __attribute__((address_space(3)))

// async global->LDS: HW writes wave-uniform LDS base + lane*16
__device__ __forceinline__ void gload16(const void* g, void* lds) {
    __builtin_amdgcn_global_load_lds((const AS1 u32*)(uintptr_t)g,
                                     (AS3 u32*)(u32)(uintptr_t)lds, 16, 0, 0);
}

__device__ __forceinline__ u16 f2bf(float f) {
    union { float f; u32 u; } v; v.f = f;
    u32 r = v.u + 0x7fffu + ((v.u >> 16) & 1u);   // RNE
    return (u16)(r >> 16);
}

// ---------------- workspace layout (bytes) ----------------
// 0        topk_idx int[2N]
// 262144   topk_w   f32[2N]
// 524288   tok      int[2N]
// 786432   wgt      f32[2N]
// 1048576  pairpos  int[2N]
// 1310720  counts[16] fill[16] offs[17] tp[17]
// 2097152  xb   bf16[N][C]
// 18874368 w1t  bf16[E][F][C]
// 27262976 w2t  bf16[E][C][F]
// 35651584 ybuf f32[2N][C]  (MODE 0 only)

// ---- gate: 64 tokens/block, 4 lanes/token, fused x->bf16 conversion ----
__global__ __launch_bounds__(256) void gate_kernel(
    const float* __restrict__ x, const float* __restrict__ gW,
    const float* __restrict__ gb, float* __restrict__ ent_out,
    int* __restrict__ tidx, float* __restrict__ tw, int* __restrict__ counts,
    u16* __restrict__ xb)
{
    __shared__ float gws[E_NUM * C_DIM];
    __shared__ float gbs[E_NUM];
    __shared__ float went[4];
    __shared__ int lc[E_NUM];
    int tid = threadIdx.x;

    for (int i = tid; i < E_NUM * C_DIM / 4; i += 256)
        ((float4*)gws)[i] = ((const float4*)gW)[i];
    if (tid < E_NUM) { gbs[tid] = gb[tid]; lc[tid] = 0; }
    __syncthreads();

    int tok = tid >> 2, q = tid & 3;
    int n = blockIdx.x * 64 + tok;
    const float* xr = x + (size_t)n * C_DIM;

    // coalesced: thread q covers c = j*16 + q*4 .. +3  (4 lanes/token -> 64B)
    float4 xv[16];
    #pragma unroll
    for (int j = 0; j < 16; j++)
        xv[j] = *(const float4*)(xr + j * 16 + q * 4);

    // fused bf16 conversion of x
    #pragma unroll
    for (int j = 0; j < 16; j++) {
        u16x4 o;
        o[0] = f2bf(xv[j].x); o[1] = f2bf(xv[j].y);
        o[2] = f2bf(xv[j].z); o[3] = f2bf(xv[j].w);
        *(u16x4*)(xb + (size_t)n * C_DIM + j * 16 + q * 4) = o;
    }

    float lg[E_NUM];
    #pragma unroll
    for (int e = 0; e < E_NUM; e++) lg[e] = 0.f;
    #pragma unroll
    for (int j = 0; j < 16; j++) {
        #pragma unroll
        for (int e = 0; e < E_NUM; e++) {
            float4 g = *(const float4*)(gws + e * C_DIM + j * 16 + q * 4);
            lg[e] += xv[j].x * g.x + xv[j].y * g.y + xv[j].z * g.z + xv[j].w * g.w;
        }
    }
    #pragma unroll
    for (int e = 0; e < E_NUM; e++) {
        lg[e] += __shfl_xor(lg[e], 1);
        lg[e] += __shfl_xor(lg[e], 2);
        lg[e] += gbs[e];
    }

    float m = lg[0];
    #pragma unroll
    for (int e = 1; e < E_NUM; e++) m = fmaxf(m, lg[e]);
    float s = 0.f, ex[E_NUM];
    #pragma unroll
    for (int e = 0; e < E_NUM; e++) { ex[e] = __expf(lg[e] - m); s += ex[e]; }
    float inv = 1.f / s;
    float ent = 0.f;
    #pragma unroll
    for (int e = 0; e < E_NUM; e++) {
        float p = ex[e] * inv;
        ent -= p * logf(p + 1e-8f);
    }

    float v0 = -1e30f, v1 = -1e30f;
    int i0 = 0, i1 = 0;
    #pragma unroll
    for (int e = 0; e < E_NUM; e++) {
        float l = lg[e];
        if (l > v0) { v1 = v0; i1 = i0; v0 = l; i0 = e; }
        else if (l > v1) { v1 = l; i1 = e; }
    }
    if (q == 0) {
        float w1e = __expf(v1 - v0);
        float z = 1.f + w1e;
        tidx[2 * n] = i0; tidx[2 * n + 1] = i1;
        tw[2 * n] = 1.f / z; tw[2 * n + 1] = w1e / z;
        atomicAdd(&lc[i0], 1);
        atomicAdd(&lc[i1], 1);
    }

    float v = ent;   // 4x duplicated per token -> scale 1/(4N)
    for (int off = 32; off > 0; off >>= 1) v += __shfl_down(v, off);
    int wid = tid >> 6, lane = tid & 63;
    if (lane == 0) went[wid] = v;
    __syncthreads();
    if (tid == 0)
        atomicAdd(ent_out, (went[0] + went[1] + went[2] + went[3]) * (1.0f / (4.0f * N_TOK)));
    if (tid < E_NUM && lc[tid]) atomicAdd(&counts[tid], lc[tid]);
}

__global__ void prefix_kernel(const int* __restrict__ counts,
                              int* __restrict__ offs, int* __restrict__ tp)
{
    if (threadIdx.x == 0 && blockIdx.x == 0) {
        int o = 0, t = 0;
        offs[0] = 0; tp[0] = 0;
        for (int e = 0; e < E_NUM; e++) {
            o += counts[e];
            t += (counts[e] + TILE_R - 1) / TILE_R;
            offs[e + 1] = o;
            tp[e + 1] = t;
        }
    }
}

__global__ __launch_bounds__(256) void scatter_kernel(
    const int* __restrict__ tidx, const float* __restrict__ tw,
    const int* __restrict__ offs, int* __restrict__ fill,
    int* __restrict__ tok, float* __restrict__ wgt, int* __restrict__ pairpos)
{
    __shared__ int lc[E_NUM], lbase[E_NUM];
    int tid = threadIdx.x;
    if (tid < E_NUM) lc[tid] = 0;
    __syncthreads();
    int n = blockIdx.x * 256 + tid;
    int e0 = tidx[2 * n], e1 = tidx[2 * n + 1];
    int r0 = atomicAdd(&lc[e0], 1);
    int r1 = atomicAdd(&lc[e1], 1);
    __syncthreads();
    if (tid < E_NUM) lbase[tid] = offs[tid] + atomicAdd(&fill[tid], lc[tid]);
    __syncthreads();
    int p0 = lbase[e0] + r0, p1 = lbase[e1] + r1;
    tok[p0] = n; wgt[p0] = tw[2 * n];     pairpos[2 * n] = p0;
    tok[p1] = n; wgt[p1] = tw[2 * n + 1]; pairpos[2 * n + 1] = p1;
}

// per-expert transpose+convert: src f32 [R][Cc] -> dst bf16 [Cc][R]
__global__ __launch_bounds__(256) void tcvt_kernel(
    const float* __restrict__ src, u16* __restrict__ dst, int R, int Cc)
{
    __shared__ float t[64][65];
    int e = blockIdx.x;
    int r0 = blockIdx.y << 6, c0 = blockIdx.z << 6;
    const float* s = src + (size_t)e * R * Cc;
    u16* d = dst + (size_t)e * R * Cc;
    int tid = threadIdx.x;
    int rr = tid >> 4, cc = (tid & 15) << 2;
    #pragma unroll
    for (int it = 0; it < 4; it++) {
        float4 v = *(const float4*)(s + (size_t)(r0 + rr + it * 16) * Cc + c0 + cc);
        t[rr + it * 16][cc] = v.x; t[rr + it * 16][cc + 1] = v.y;
        t[rr + it * 16][cc + 2] = v.z; t[rr + it * 16][cc + 3] = v.w;
    }
    __syncthreads();
    int cr = tid >> 3, rq = (tid & 7) << 3;
    #pragma unroll
    for (int it = 0; it < 2; it++) {
        int c = cr + it * 32;
        u16x8 o;
        #pragma unroll
        for (int j = 0; j < 8; j++) o[j] = f2bf(t[rq + j][c]);
        *(u16x8*)(d + (size_t)(c0 + c) * R + r0 + rq) = o;
    }
}

// ---- FFN: 128-token tile, 8 waves, 32x32x16 MFMA, frag-linear LDS ----
// smem: xs 64K @0 | w1s 32K @65536 | w2s 32K @98304 | b1s 4K @131072
//       s_tok @135168 | s_w @135680
#define XS_OFF  0
#define W1S_OFF 65536
#define W2S_OFF 98304
#define B1S_OFF 131072

template <int MODE>
__global__ __launch_bounds__(512, 2) void ffn_mfma(
    const u16* __restrict__ xb, const u16* __restrict__ w1t,
    const u16* __restrict__ w2t, const float* __restrict__ b1,
    const float* __restrict__ b2, const int* __restrict__ tok,
    const float* __restrict__ wgt, const int* __restrict__ offs,
    const int* __restrict__ tp, float* __restrict__ ybuf,
    float* __restrict__ out)
{
    __shared__ __align__(1024) char smem[136192];
    int* s_tok = (int*)(smem + 135168);
    float* s_w = (float*)(smem + 135680);
    float* b1s = (float*)(smem + B1S_OFF);

    int b = blockIdx.x;
    if (b >= tp[E_NUM]) return;
    int e = 0;
    while (b >= tp[e + 1]) e++;
    int base = offs[e] + ((b - tp[e]) << 7);
    int rows = offs[e + 1] - base; if (rows > TILE_R) rows = TILE_R;

    int tid = threadIdx.x;
    int lane = tid & 63, wid = tid >> 6;
    int hi = lane >> 5;
    int wr = wid >> 1, wc = wid & 1;

    const u16* w1e = w1t + (size_t)e * (F_DIM * C_DIM);   // [F][C]
    const u16* w2e = w2t + (size_t)e * (C_DIM * F_DIM);   // [C][F]
    const float* b1e = b1 + e * F_DIM;
    const float* b2e = b2 + e * C_DIM;

    if (tid < TILE_R) {
        int src = (tid < rows) ? base + tid : base;
        s_tok[tid] = tok[src];
        s_w[tid] = (tid < rows) ? wgt[src] : 0.f;
    }
    if (tid < 256) ((float4*)b1s)[tid] = ((const float4*)b1e)[tid];
    __syncthreads();

    // stage x frags once: [mtile 4][ks 16] -> frag idx 0..63
    #pragma unroll
    for (int i = 0; i < 8; i++) {
        int idx = (wid << 3) + i;
        int row = ((idx >> 4) << 5) + (lane & 31);
        const u16* src = xb + ((size_t)s_tok[row] << 8) + ((idx & 15) << 4) + (hi << 3);
        gload16(src, smem + (idx << 10));
    }
    // stage w1 chunk 0: [ftile 2][ks 16]
    #pragma unroll
    for (int i = 0; i < 4; i++) {
        int idx = (wid << 2) + i;
        int f = ((idx >> 4) << 5) + (lane & 31);
        const u16* src = w1e + ((size_t)f << 8) + ((idx & 15) << 4) + (hi << 3);
        gload16(src, smem + W1S_OFF + (idx << 10));
    }
    __syncthreads();

    f32x16 acc2[8];
    #pragma unroll
    for (int ct = 0; ct < 8; ct++) acc2[ct] = (f32x16)(0.0f);

    const char* w1base = smem + W1S_OFF + (wc << 14);
    const char* xsbase = smem + (wr << 14);

    for (int ch = 0; ch < NCH; ch++) {
        // stage w2 chunk (overlaps phase 1): [ctile 8][gks 4]
        #pragma unroll
        for (int i = 0; i < 4; i++) {
            int idx = (wid << 2) + i;
            int c = ((idx >> 2) << 5) + (lane & 31);
            const u16* src = w2e + ((size_t)c << 10) + (ch << 6) + ((idx & 3) << 4) + (hi << 3);
            gload16(src, smem + W2S_OFF + (idx << 10));
        }

        // ---- phase 1: Ht = W1 x X^T (swapped) -> D[f][m], col=m=lane&31 ----
        f32x16 acc1 = (f32x16)(0.0f);
        #pragma unroll
        for (int ks = 0; ks < 16; ks++) {
            bf16x8 a = *(const bf16x8*)(w1base + (ks << 10) + (lane << 4));
            bf16x8 bx = *(const bf16x8*)(xsbase + (ks << 10) + (lane << 4));
            acc1 = __builtin_amdgcn_mfma_f32_32x32x16_bf16(a, bx, acc1, 0, 0, 0);
        }

        // bias + relu, pack to bf16 pairs, permlane half-swap -> B-frags in regs
        float h[16];
        #pragma unroll
        for (int r = 0; r < 16; r++) {
            int fl = (wc << 5) + (r & 3) + ((r >> 2) << 3) + (hi << 2);
            h[r] = fmaxf(acc1[r] + b1s[(ch << 6) + fl], 0.f);
        }
        u32 w[8];
        #pragma unroll
        for (int t = 0; t < 8; t++)
            asm("v_cvt_pk_bf16_f32 %0, %1, %2" : "=v"(w[t]) : "v"(h[2 * t]), "v"(h[2 * t + 1]));
        asm volatile("v_permlane32_swap_b32 %0, %1" : "+v"(w[0]), "+v"(w[2]));
        asm volatile("v_permlane32_swap_b32 %0, %1" : "+v"(w[1]), "+v"(w[3]));
        asm volatile("v_permlane32_swap_b32 %0, %1" : "+v"(w[4]), "+v"(w[6]));
        asm volatile("v_permlane32_swap_b32 %0, %1" : "+v"(w[5]), "+v"(w[7]));
        union { u32x4 u; bf16x8 v; } fr0, fr1;
        fr0.u = (u32x4){w[0], w[1], w[2], w[3]};
        fr1.u = (u32x4){w[4], w[5], w[6], w[7]};

        __syncthreads();   // p1 reads done; w2s arrived

        if (ch + 1 < NCH) {
            #pragma unroll
            for (int i = 0; i < 4; i++) {
                int idx = (wid << 2) + i;
                int f = ((ch + 1) << 6) + ((idx >> 4) << 5) + (lane & 31);
                const u16* src = w1e + ((size_t)f << 8) + ((idx & 15) << 4) + (hi << 3);
                gload16(src, smem + W1S_OFF + (idx << 10));
            }
        }

        // ---- phase 2 (K-split): acc2[ct] += W2frag(ct, 2wc+s) x Hfrag(s) ----
        #pragma unroll
        for (int s = 0; s < 2; s++) {
            bf16x8 bh = s ? fr1.v : fr0.v;
            const char* w2b = smem + W2S_OFF + (((wc << 1) + s) << 10) + (lane << 4);
            #pragma unroll
            for (int ct = 0; ct < 8; ct++) {
                bf16x8 a = *(const bf16x8*)(w2b + (ct << 12));
                acc2[ct] = __builtin_amdgcn_mfma_f32_32x32x16_bf16(a, bh, acc2[ct], 0, 0, 0);
            }
        }
        __syncthreads();   // p2 w2s reads done; w1s(ch+1) arrived
    }

    // ---- cross-wc pair reduction via LDS (reuse xs/w1s/w2s space) ----
    float* red = (float*)smem;
    float* myslot = red + (wid << 12);            // 16KB per wave
    int sendb = wc ? 0 : 4;
    #pragma unroll
    for (int j = 0; j < 4; j++)
        #pragma unroll
        for (int rq = 0; rq < 4; rq++) {
            float4 v = {acc2[sendb + j][4 * rq], acc2[sendb + j][4 * rq + 1],
                        acc2[sendb + j][4 * rq + 2], acc2[sendb + j][4 * rq + 3]};
            *(float4*)(myslot + ((((j << 2) + rq) << 6) + lane) * 4) = v;
        }
    __syncthreads();
    float* pslot = red + ((wid ^ 1) << 12);
    int keep = wc ? 4 : 0;
    #pragma unroll
    for (int j = 0; j < 4; j++)
        #pragma unroll
        for (int rq = 0; rq < 4; rq++) {
            float4 v = *(const float4*)(pslot + ((((j << 2) + rq) << 6) + lane) * 4);
            acc2[keep + j][4 * rq]     += v.x;
            acc2[keep + j][4 * rq + 1] += v.y;
            acc2[keep + j][4 * rq + 2] += v.z;
            acc2[keep + j][4 * rq + 3] += v.w;
        }

    int m = (wr << 5) + (lane & 31);
    if (m < rows) {
        if (MODE == 0) {
            float* yr = ybuf + ((size_t)(base + m) << 8);
            #pragma unroll
            for (int j = 0; j < 4; j++) {
                int ct = keep + j;
                #pragma unroll
                for (int rq = 0; rq < 4; rq++) {
                    int c = (ct << 5) + (rq << 3) + (hi << 2);
                    float4 v = {acc2[ct][4 * rq], acc2[ct][4 * rq + 1],
                                acc2[ct][4 * rq + 2], acc2[ct][4 * rq + 3]};
                    *(float4*)(yr + c) = v;
                }
            }
        } else {
            float wgt_m = s_w[m];
            float* orow = out + ((size_t)s_tok[m] << 8);
            #pragma unroll
            for (int j = 0; j < 4; j++) {
                int ct = keep + j;
                #pragma unroll
                for (int rq = 0; rq < 4; rq++) {
                    int c = (ct << 5) + (rq << 3) + (hi << 2);
                    #pragma unroll
                    for (int l = 0; l < 4; l++)
                        atomicAdd(&orow[c + l], wgt_m * (acc2[ct][4 * rq + l] + b2e[c + l]));
                }
            }
        }
    }
}

__global__ __launch_bounds__(256) void combine_kernel(
    const float* __restrict__ ybuf, const int* __restrict__ tidx,
    const float* __restrict__ tw, const int* __restrict__ pairpos,
    const float* __restrict__ b2, float* __restrict__ out)
{
    int idx = blockIdx.x * 256 + threadIdx.x;
    int n = idx >> 6;
    int q = (idx & 63) << 2;
    int e0 = tidx[2 * n], e1 = tidx[2 * n + 1];
    float w0 = tw[2 * n], w1 = tw[2 * n + 1];
    int p0 = pairpos[2 * n], p1 = pairpos[2 * n + 1];
    float4 y0 = *(const float4*)(ybuf + ((size_t)p0 << 8) + q);
    float4 y1 = *(const float4*)(ybuf + ((size_t)p1 << 8) + q);
    float4 c0 = *(const float4*)(b2 + (e0 << 8) + q);
    float4 c1 = *(const float4*)(b2 + (e1 << 8) + q);
    float4 o;
    o.x = w0 * (y0.x + c0.x) + w1 * (y1.x + c1.x);
    o.y = w0 * (y0.y + c0.y) + w1 * (y1.y + c1.y);
    o.z = w0 * (y0.z + c0.z) + w1 * (y1.z + c1.z);
    o.w = w0 * (y0.w + c0.w) + w1 * (y1.w + c1.w);
    *(float4*)(out + ((size_t)n << 8) + q) = o;
}

extern "C" void kernel_launch(void* const* d_in, const int* in_sizes, int n_in,
                              void* d_out, int out_size, void* d_ws, size_t ws_size,
                              hipStream_t stream)
{
    const float* x   = (const float*)d_in[0];
    const float* gW  = (const float*)d_in[1];
    const float* gb  = (const float*)d_in[2];
    const float* W1  = (const float*)d_in[3];
    const float* b1  = (const float*)d_in[4];
    const float* W2  = (const float*)d_in[5];
    const float* b2  = (const float*)d_in[6];
    float* out = (float*)d_out;

    char* ws = (char*)d_ws;
    int*   topk_idx = (int*)(ws + 0);
    float* topk_w   = (float*)(ws + 262144);
    int*   tok      = (int*)(ws + 524288);
    float* wgt      = (float*)(ws + 786432);
    int*   pairpos  = (int*)(ws + 1048576);
    int*   counts   = (int*)(ws + 1310720);
    int*   fill     = (int*)(ws + 1310784);
    int*   offs     = (int*)(ws + 1310848);
    int*   tp       = (int*)(ws + 1310916);

    const size_t XB_OFF  = 2097152;
    const size_t W1T_OFF = 18874368;
    const size_t W2T_OFF = 27262976;
    const size_t Y_OFF   = 35651584;
    const size_t WS_FULL = Y_OFF + (size_t)2 * N_TOK * C_DIM * 4;

    u16* xb  = (u16*)(ws + XB_OFF);
    u16* w1t = (u16*)(ws + W1T_OFF);
    u16* w2t = (u16*)(ws + W2T_OFF);
    float* ybuf = (float*)(ws + Y_OFF);

    int mode = (ws_size >= WS_FULL) ? 0 : 1;

    hipMemsetAsync(d_out, 0, (size_t)(N_TOK * C_DIM + 1) * sizeof(float), stream);
    hipMemsetAsync(counts, 0, 2 * E_NUM * sizeof(int), stream);

    float* ent_out = out + (size_t)N_TOK * C_DIM;

    gate_kernel<<<N_TOK / 64, 256, 0, stream>>>(x, gW, gb, ent_out,
                                                topk_idx, topk_w, counts, xb);
    prefix_kernel<<<1, 64, 0, stream>>>(counts, offs, tp);
    scatter_kernel<<<N_TOK / 256, 256, 0, stream>>>(topk_idx, topk_w, offs,
                                                    fill, tok, wgt, pairpos);
    tcvt_kernel<<<dim3(E_NUM, C_DIM / 64, F_DIM / 64), 256, 0, stream>>>(W1, w1t, C_DIM, F_DIM);
    tcvt_kernel<<<dim3(E_NUM, F_DIM / 64, C_DIM / 64), 256, 0, stream>>>(W2, w2t, F_DIM, C_DIM);

    if (mode == 0) {
        ffn_mfma<0><<<544, 512, 0, stream>>>(xb, w1t, w2t, b1, b2, tok, wgt,
                                             offs, tp, ybuf, out);
        combine_kernel<<<N_TOK * 64 / 256, 256, 0, stream>>>(ybuf, topk_idx,
                                                             topk_w, pairpos, b2, out);
    } else {
        ffn_mfma<1><<<544, 512, 0, stream>>>(xb, w1t, w2t, b1, b2, tok, wgt,
                                             offs, tp, ybuf, out);
    }
}

// Round 4
// 249.701 us; speedup vs baseline: 4.5684x; 4.5684x over previous
//
#include <hip/hip_runtime.h>
#include <hip/hip_bf16.h>
#include <math.h>

#define N_TOK 32768
#define C_DIM 256
#define F_DIM 1024
#define E_NUM 16
#define TILE_R 128
#define NCH 16

typedef unsigned short u16;
typedef unsigned int u32;
typedef __attribute__((ext_vector_type(4))) u16 u16x4;
typedef __attribute__((ext_vector_type(8))) u16 u16x8;
typedef __attribute__((ext_vector_type(8))) short bf16x8;
typedef __attribute__((ext_vector_type(4))) u32 u32x4;
typedef __attribute__((ext_vector_type(4))) float f32x4;
typedef __attribute__((ext_vector_type(16))) float f32x16;

#define AS1 __attribute__((address_space(1)))
#define AS3 __attribute__((address_space(3)))

// async global->LDS: HW writes wave-uniform LDS base + lane*16
__device__ __forceinline__ void gload16(const void* g, void* lds) {
    __builtin_amdgcn_global_load_lds((const AS1 u32*)(uintptr_t)g,
                                     (AS3 u32*)(u32)(uintptr_t)lds, 16, 0, 0);
}

__device__ __forceinline__ u16 f2bf(float f) {
    union { float f; u32 u; } v; v.f = f;
    u32 r = v.u + 0x7fffu + ((v.u >> 16) & 1u);   // RNE
    return (u16)(r >> 16);
}

// ---------------- workspace layout (bytes) ----------------
// 0        topk_idx int[2N]
// 262144   topk_w   f32[2N]
// 524288   tok      int[2N]
// 786432   wgt      f32[2N]
// 1048576  pairpos  int[2N]
// 1310720  counts[16] fill[16] offs[17] tp[17]
// 2097152  xb   bf16[N][C]
// 18874368 w1t  bf16[E][F][C]
// 27262976 w2t  bf16[E][C][F]
// 35651584 ybuf f32[2N][C]  (MODE 0 only)

// ---- gate: 64 tokens/block, 4 lanes/token, fused x->bf16 conversion ----
__global__ __launch_bounds__(256) void gate_kernel(
    const float* __restrict__ x, const float* __restrict__ gW,
    const float* __restrict__ gb, float* __restrict__ ent_out,
    int* __restrict__ tidx, float* __restrict__ tw, int* __restrict__ counts,
    u16* __restrict__ xb)
{
    __shared__ float gws[E_NUM * C_DIM];
    __shared__ float gbs[E_NUM];
    __shared__ float went[4];
    __shared__ int lc[E_NUM];
    int tid = threadIdx.x;

    for (int i = tid; i < E_NUM * C_DIM / 4; i += 256)
        ((float4*)gws)[i] = ((const float4*)gW)[i];
    if (tid < E_NUM) { gbs[tid] = gb[tid]; lc[tid] = 0; }
    __syncthreads();

    int tok = tid >> 2, q = tid & 3;
    int n = blockIdx.x * 64 + tok;
    const float* xr = x + (size_t)n * C_DIM;

    float4 xv[16];
    #pragma unroll
    for (int j = 0; j < 16; j++)
        xv[j] = *(const float4*)(xr + j * 16 + q * 4);

    #pragma unroll
    for (int j = 0; j < 16; j++) {
        u16x4 o;
        o[0] = f2bf(xv[j].x); o[1] = f2bf(xv[j].y);
        o[2] = f2bf(xv[j].z); o[3] = f2bf(xv[j].w);
        *(u16x4*)(xb + (size_t)n * C_DIM + j * 16 + q * 4) = o;
    }

    float lg[E_NUM];
    #pragma unroll
    for (int e = 0; e < E_NUM; e++) lg[e] = 0.f;
    #pragma unroll
    for (int j = 0; j < 16; j++) {
        #pragma unroll
        for (int e = 0; e < E_NUM; e++) {
            float4 g = *(const float4*)(gws + e * C_DIM + j * 16 + q * 4);
            lg[e] += xv[j].x * g.x + xv[j].y * g.y + xv[j].z * g.z + xv[j].w * g.w;
        }
    }
    #pragma unroll
    for (int e = 0; e < E_NUM; e++) {
        lg[e] += __shfl_xor(lg[e], 1);
        lg[e] += __shfl_xor(lg[e], 2);
        lg[e] += gbs[e];
    }

    float m = lg[0];
    #pragma unroll
    for (int e = 1; e < E_NUM; e++) m = fmaxf(m, lg[e]);
    float s = 0.f, ex[E_NUM];
    #pragma unroll
    for (int e = 0; e < E_NUM; e++) { ex[e] = __expf(lg[e] - m); s += ex[e]; }
    float inv = 1.f / s;
    float ent = 0.f;
    #pragma unroll
    for (int e = 0; e < E_NUM; e++) {
        float p = ex[e] * inv;
        ent -= p * logf(p + 1e-8f);
    }

    float v0 = -1e30f, v1 = -1e30f;
    int i0 = 0, i1 = 0;
    #pragma unroll
    for (int e = 0; e < E_NUM; e++) {
        float l = lg[e];
        if (l > v0) { v1 = v0; i1 = i0; v0 = l; i0 = e; }
        else if (l > v1) { v1 = l; i1 = e; }
    }
    if (q == 0) {
        float w1e = __expf(v1 - v0);
        float z = 1.f + w1e;
        tidx[2 * n] = i0; tidx[2 * n + 1] = i1;
        tw[2 * n] = 1.f / z; tw[2 * n + 1] = w1e / z;
        atomicAdd(&lc[i0], 1);
        atomicAdd(&lc[i1], 1);
    }

    float v = ent;   // 4x duplicated per token -> scale 1/(4N)
    for (int off = 32; off > 0; off >>= 1) v += __shfl_down(v, off);
    int wid = tid >> 6, lane = tid & 63;
    if (lane == 0) went[wid] = v;
    __syncthreads();
    if (tid == 0)
        atomicAdd(ent_out, (went[0] + went[1] + went[2] + went[3]) * (1.0f / (4.0f * N_TOK)));
    if (tid < E_NUM && lc[tid]) atomicAdd(&counts[tid], lc[tid]);
}

__global__ void prefix_kernel(const int* __restrict__ counts,
                              int* __restrict__ offs, int* __restrict__ tp)
{
    if (threadIdx.x == 0 && blockIdx.x == 0) {
        int o = 0, t = 0;
        offs[0] = 0; tp[0] = 0;
        for (int e = 0; e < E_NUM; e++) {
            o += counts[e];
            t += (counts[e] + TILE_R - 1) / TILE_R;
            offs[e + 1] = o;
            tp[e + 1] = t;
        }
    }
}

__global__ __launch_bounds__(256) void scatter_kernel(
    const int* __restrict__ tidx, const float* __restrict__ tw,
    const int* __restrict__ offs, int* __restrict__ fill,
    int* __restrict__ tok, float* __restrict__ wgt, int* __restrict__ pairpos)
{
    __shared__ int lc[E_NUM], lbase[E_NUM];
    int tid = threadIdx.x;
    if (tid < E_NUM) lc[tid] = 0;
    __syncthreads();
    int n = blockIdx.x * 256 + tid;
    int e0 = tidx[2 * n], e1 = tidx[2 * n + 1];
    int r0 = atomicAdd(&lc[e0], 1);
    int r1 = atomicAdd(&lc[e1], 1);
    __syncthreads();
    if (tid < E_NUM) lbase[tid] = offs[tid] + atomicAdd(&fill[tid], lc[tid]);
    __syncthreads();
    int p0 = lbase[e0] + r0, p1 = lbase[e1] + r1;
    tok[p0] = n; wgt[p0] = tw[2 * n];     pairpos[2 * n] = p0;
    tok[p1] = n; wgt[p1] = tw[2 * n + 1]; pairpos[2 * n + 1] = p1;
}

// per-expert transpose+convert: src f32 [R][Cc] -> dst bf16 [Cc][R]
__global__ __launch_bounds__(256) void tcvt_kernel(
    const float* __restrict__ src, u16* __restrict__ dst, int R, int Cc)
{
    __shared__ float t[64][65];
    int e = blockIdx.x;
    int r0 = blockIdx.y << 6, c0 = blockIdx.z << 6;
    const float* s = src + (size_t)e * R * Cc;
    u16* d = dst + (size_t)e * R * Cc;
    int tid = threadIdx.x;
    int rr = tid >> 4, cc = (tid & 15) << 2;
    #pragma unroll
    for (int it = 0; it < 4; it++) {
        float4 v = *(const float4*)(s + (size_t)(r0 + rr + it * 16) * Cc + c0 + cc);
        t[rr + it * 16][cc] = v.x; t[rr + it * 16][cc + 1] = v.y;
        t[rr + it * 16][cc + 2] = v.z; t[rr + it * 16][cc + 3] = v.w;
    }
    __syncthreads();
    int cr = tid >> 3, rq = (tid & 7) << 3;
    #pragma unroll
    for (int it = 0; it < 2; it++) {
        int c = cr + it * 32;
        u16x8 o;
        #pragma unroll
        for (int j = 0; j < 8; j++) o[j] = f2bf(t[rq + j][c]);
        *(u16x8*)(d + (size_t)(c0 + c) * R + r0 + rq) = o;
    }
}

// ---- FFN: 128-token tile, 8 waves, 32x32x16 MFMA, frag-linear LDS ----
#define XS_OFF  0
#define W1S_OFF 65536
#define W2S_OFF 98304
#define B1S_OFF 131072

// All acc2 accesses must be compile-time-constant (rule #20): macro-ized
// epilogue bodies with literal base index B, selected by uniform wc branch.
#define STORE_HALF(B)                                                         \
    _Pragma("unroll")                                                         \
    for (int j = 0; j < 4; j++) {                                             \
        _Pragma("unroll")                                                     \
        for (int rq = 0; rq < 4; rq++) {                                      \
            float4 v = {acc2[(B) + j][4 * rq],     acc2[(B) + j][4 * rq + 1], \
                        acc2[(B) + j][4 * rq + 2], acc2[(B) + j][4 * rq + 3]};\
            *(float4*)(myslot + ((((j << 2) + rq) << 6) + lane) * 4) = v;     \
        }                                                                     \
    }

#define REDUCE_HALF(B)                                                        \
    _Pragma("unroll")                                                         \
    for (int j = 0; j < 4; j++) {                                             \
        _Pragma("unroll")                                                     \
        for (int rq = 0; rq < 4; rq++) {                                      \
            float4 v = *(const float4*)(pslot + ((((j << 2) + rq) << 6) + lane) * 4); \
            acc2[(B) + j][4 * rq]     += v.x;                                 \
            acc2[(B) + j][4 * rq + 1] += v.y;                                 \
            acc2[(B) + j][4 * rq + 2] += v.z;                                 \
            acc2[(B) + j][4 * rq + 3] += v.w;                                 \
        }                                                                     \
    }

#define WRITE_Y(B)                                                            \
    _Pragma("unroll")                                                         \
    for (int j = 0; j < 4; j++) {                                             \
        _Pragma("unroll")                                                     \
        for (int rq = 0; rq < 4; rq++) {                                      \
            int c = (((B) + j) << 5) + (rq << 3) + (hi << 2);                 \
            float4 v = {acc2[(B) + j][4 * rq],     acc2[(B) + j][4 * rq + 1], \
                        acc2[(B) + j][4 * rq + 2], acc2[(B) + j][4 * rq + 3]};\
            *(float4*)(yr + c) = v;                                           \
        }                                                                     \
    }

#define WRITE_ATOMIC(B)                                                       \
    _Pragma("unroll")                                                         \
    for (int j = 0; j < 4; j++) {                                             \
        _Pragma("unroll")                                                     \
        for (int rq = 0; rq < 4; rq++) {                                      \
            int c = (((B) + j) << 5) + (rq << 3) + (hi << 2);                 \
            _Pragma("unroll")                                                 \
            for (int l = 0; l < 4; l++)                                       \
                atomicAdd(&orow[c + l],                                       \
                          wgt_m * (acc2[(B) + j][4 * rq + l] + b2e[c + l]));  \
        }                                                                     \
    }

template <int MODE>
__global__ __launch_bounds__(512, 2) void ffn_mfma(
    const u16* __restrict__ xb, const u16* __restrict__ w1t,
    const u16* __restrict__ w2t, const float* __restrict__ b1,
    const float* __restrict__ b2, const int* __restrict__ tok,
    const float* __restrict__ wgt, const int* __restrict__ offs,
    const int* __restrict__ tp, float* __restrict__ ybuf,
    float* __restrict__ out)
{
    __shared__ __align__(1024) char smem[136192];
    int* s_tok = (int*)(smem + 135168);
    float* s_w = (float*)(smem + 135680);
    float* b1s = (float*)(smem + B1S_OFF);

    int b = blockIdx.x;
    if (b >= tp[E_NUM]) return;
    int e = 0;
    while (b >= tp[e + 1]) e++;
    int base = offs[e] + ((b - tp[e]) << 7);
    int rows = offs[e + 1] - base; if (rows > TILE_R) rows = TILE_R;

    int tid = threadIdx.x;
    int lane = tid & 63, wid = tid >> 6;
    int hi = lane >> 5;
    int wr = wid >> 1, wc = wid & 1;

    const u16* w1e = w1t + (size_t)e * (F_DIM * C_DIM);   // [F][C]
    const u16* w2e = w2t + (size_t)e * (C_DIM * F_DIM);   // [C][F]
    const float* b1e = b1 + e * F_DIM;
    const float* b2e = b2 + e * C_DIM;

    if (tid < TILE_R) {
        int src = (tid < rows) ? base + tid : base;
        s_tok[tid] = tok[src];
        s_w[tid] = (tid < rows) ? wgt[src] : 0.f;
    }
    if (tid < 256) ((float4*)b1s)[tid] = ((const float4*)b1e)[tid];
    __syncthreads();

    // stage x frags once: [mtile 4][ks 16] -> frag idx 0..63
    #pragma unroll
    for (int i = 0; i < 8; i++) {
        int idx = (wid << 3) + i;
        int row = ((idx >> 4) << 5) + (lane & 31);
        const u16* src = xb + ((size_t)s_tok[row] << 8) + ((idx & 15) << 4) + (hi << 3);
        gload16(src, smem + (idx << 10));
    }
    // stage w1 chunk 0: [ftile 2][ks 16]
    #pragma unroll
    for (int i = 0; i < 4; i++) {
        int idx = (wid << 2) + i;
        int f = ((idx >> 4) << 5) + (lane & 31);
        const u16* src = w1e + ((size_t)f << 8) + ((idx & 15) << 4) + (hi << 3);
        gload16(src, smem + W1S_OFF + (idx << 10));
    }
    __syncthreads();

    f32x16 acc2[8];
    #pragma unroll
    for (int ct = 0; ct < 8; ct++) acc2[ct] = (f32x16)(0.0f);

    const char* w1base = smem + W1S_OFF + (wc << 14);
    const char* xsbase = smem + (wr << 14);

    for (int ch = 0; ch < NCH; ch++) {
        // stage w2 chunk (overlaps phase 1): [ctile 8][gks 4]
        #pragma unroll
        for (int i = 0; i < 4; i++) {
            int idx = (wid << 2) + i;
            int c = ((idx >> 2) << 5) + (lane & 31);
            const u16* src = w2e + ((size_t)c << 10) + (ch << 6) + ((idx & 3) << 4) + (hi << 3);
            gload16(src, smem + W2S_OFF + (idx << 10));
        }

        // ---- phase 1: Ht = W1 x X^T (swapped) -> D[f][m], col=m=lane&31 ----
        f32x16 acc1 = (f32x16)(0.0f);
        #pragma unroll
        for (int ks = 0; ks < 16; ks++) {
            bf16x8 a = *(const bf16x8*)(w1base + (ks << 10) + (lane << 4));
            bf16x8 bx = *(const bf16x8*)(xsbase + (ks << 10) + (lane << 4));
            acc1 = __builtin_amdgcn_mfma_f32_32x32x16_bf16(a, bx, acc1, 0, 0, 0);
        }

        // bias + relu, pack to bf16 pairs, permlane half-swap -> B-frags in regs
        float h[16];
        #pragma unroll
        for (int r = 0; r < 16; r++) {
            int fl = (wc << 5) + (r & 3) + ((r >> 2) << 3) + (hi << 2);
            h[r] = fmaxf(acc1[r] + b1s[(ch << 6) + fl], 0.f);
        }
        u32 w[8];
        #pragma unroll
        for (int t = 0; t < 8; t++)
            asm("v_cvt_pk_bf16_f32 %0, %1, %2" : "=v"(w[t]) : "v"(h[2 * t]), "v"(h[2 * t + 1]));
        asm volatile("v_permlane32_swap_b32 %0, %1" : "+v"(w[0]), "+v"(w[2]));
        asm volatile("v_permlane32_swap_b32 %0, %1" : "+v"(w[1]), "+v"(w[3]));
        asm volatile("v_permlane32_swap_b32 %0, %1" : "+v"(w[4]), "+v"(w[6]));
        asm volatile("v_permlane32_swap_b32 %0, %1" : "+v"(w[5]), "+v"(w[7]));
        union { u32x4 u; bf16x8 v; } fr0, fr1;
        fr0.u = (u32x4){w[0], w[1], w[2], w[3]};
        fr1.u = (u32x4){w[4], w[5], w[6], w[7]};

        __syncthreads();   // p1 reads done; w2s arrived

        if (ch + 1 < NCH) {
            #pragma unroll
            for (int i = 0; i < 4; i++) {
                int idx = (wid << 2) + i;
                int f = ((ch + 1) << 6) + ((idx >> 4) << 5) + (lane & 31);
                const u16* src = w1e + ((size_t)f << 8) + ((idx & 15) << 4) + (hi << 3);
                gload16(src, smem + W1S_OFF + (idx << 10));
            }
        }

        // ---- phase 2 (K-split): acc2[ct] += W2frag(ct, 2wc+s) x Hfrag(s) ----
        #pragma unroll
        for (int s = 0; s < 2; s++) {
            bf16x8 bh = s ? fr1.v : fr0.v;
            const char* w2b = smem + W2S_OFF + (((wc << 1) + s) << 10) + (lane << 4);
            #pragma unroll
            for (int ct = 0; ct < 8; ct++) {
                bf16x8 a = *(const bf16x8*)(w2b + (ct << 12));
                acc2[ct] = __builtin_amdgcn_mfma_f32_32x32x16_bf16(a, bh, acc2[ct], 0, 0, 0);
            }
        }
        __syncthreads();   // p2 w2s reads done; w1s(ch+1) arrived
    }

    // ---- cross-wc pair reduction via LDS (static acc2 indices only) ----
    float* red = (float*)smem;
    float* myslot = red + (wid << 12);            // 16KB per wave
    if (wc == 0) { STORE_HALF(4) } else { STORE_HALF(0) }
    __syncthreads();
    float* pslot = red + ((wid ^ 1) << 12);
    if (wc == 0) { REDUCE_HALF(0) } else { REDUCE_HALF(4) }

    int m = (wr << 5) + (lane & 31);
    if (m < rows) {
        if (MODE == 0) {
            float* yr = ybuf + ((size_t)(base + m) << 8);
            if (wc == 0) { WRITE_Y(0) } else { WRITE_Y(4) }
        } else {
            float wgt_m = s_w[m];
            float* orow = out + ((size_t)s_tok[m] << 8);
            if (wc == 0) { WRITE_ATOMIC(0) } else { WRITE_ATOMIC(4) }
        }
    }
}

__global__ __launch_bounds__(256) void combine_kernel(
    const float* __restrict__ ybuf, const int* __restrict__ tidx,
    const float* __restrict__ tw, const int* __restrict__ pairpos,
    const float* __restrict__ b2, float* __restrict__ out)
{
    int idx = blockIdx.x * 256 + threadIdx.x;
    int n = idx >> 6;
    int q = (idx & 63) << 2;
    int e0 = tidx[2 * n], e1 = tidx[2 * n + 1];
    float w0 = tw[2 * n], w1 = tw[2 * n + 1];
    int p0 = pairpos[2 * n], p1 = pairpos[2 * n + 1];
    float4 y0 = *(const float4*)(ybuf + ((size_t)p0 << 8) + q);
    float4 y1 = *(const float4*)(ybuf + ((size_t)p1 << 8) + q);
    float4 c0 = *(const float4*)(b2 + (e0 << 8) + q);
    float4 c1 = *(const float4*)(b2 + (e1 << 8) + q);
    float4 o;
    o.x = w0 * (y0.x + c0.x) + w1 * (y1.x + c1.x);
    o.y = w0 * (y0.y + c0.y) + w1 * (y1.y + c1.y);
    o.z = w0 * (y0.z + c0.z) + w1 * (y1.z + c1.z);
    o.w = w0 * (y0.w + c0.w) + w1 * (y1.w + c1.w);
    *(float4*)(out + ((size_t)n << 8) + q) = o;
}

extern "C" void kernel_launch(void* const* d_in, const int* in_sizes, int n_in,
                              void* d_out, int out_size, void* d_ws, size_t ws_size,
                              hipStream_t stream)
{
    const float* x   = (const float*)d_in[0];
    const float* gW  = (const float*)d_in[1];
    const float* gb  = (const float*)d_in[2];
    const float* W1  = (const float*)d_in[3];
    const float* b1  = (const float*)d_in[4];
    const float* W2  = (const float*)d_in[5];
    const float* b2  = (const float*)d_in[6];
    float* out = (float*)d_out;

    char* ws = (char*)d_ws;
    int*   topk_idx = (int*)(ws + 0);
    float* topk_w   = (float*)(ws + 262144);
    int*   tok      = (int*)(ws + 524288);
    float* wgt      = (float*)(ws + 786432);
    int*   pairpos  = (int*)(ws + 1048576);
    int*   counts   = (int*)(ws + 1310720);
    int*   fill     = (int*)(ws + 1310784);
    int*   offs     = (int*)(ws + 1310848);
    int*   tp       = (int*)(ws + 1310916);

    const size_t XB_OFF  = 2097152;
    const size_t W1T_OFF = 18874368;
    const size_t W2T_OFF = 27262976;
    const size_t Y_OFF   = 35651584;
    const size_t WS_FULL = Y_OFF + (size_t)2 * N_TOK * C_DIM * 4;

    u16* xb  = (u16*)(ws + XB_OFF);
    u16* w1t = (u16*)(ws + W1T_OFF);
    u16* w2t = (u16*)(ws + W2T_OFF);
    float* ybuf = (float*)(ws + Y_OFF);

    int mode = (ws_size >= WS_FULL) ? 0 : 1;

    hipMemsetAsync(d_out, 0, (size_t)(N_TOK * C_DIM + 1) * sizeof(float), stream);
    hipMemsetAsync(counts, 0, 2 * E_NUM * sizeof(int), stream);

    float* ent_out = out + (size_t)N_TOK * C_DIM;

    gate_kernel<<<N_TOK / 64, 256, 0, stream>>>(x, gW, gb, ent_out,
                                                topk_idx, topk_w, counts, xb);
    prefix_kernel<<<1, 64, 0, stream>>>(counts, offs, tp);
    scatter_kernel<<<N_TOK / 256, 256, 0, stream>>>(topk_idx, topk_w, offs,
                                                    fill, tok, wgt, pairpos);
    tcvt_kernel<<<dim3(E_NUM, C_DIM / 64, F_DIM / 64), 256, 0, stream>>>(W1, w1t, C_DIM, F_DIM);
    tcvt_kernel<<<dim3(E_NUM, F_DIM / 64, C_DIM / 64), 256, 0, stream>>>(W2, w2t, F_DIM, C_DIM);

    if (mode == 0) {
        ffn_mfma<0><<<544, 512, 0, stream>>>(xb, w1t, w2t, b1, b2, tok, wgt,
                                             offs, tp, ybuf, out);
        combine_kernel<<<N_TOK * 64 / 256, 256, 0, stream>>>(ybuf, topk_idx,
                                                             topk_w, pairpos, b2, out);
    } else {
        ffn_mfma<1><<<544, 512, 0, stream>>>(xb, w1t, w2t, b1, b2, tok, wgt,
                                             offs, tp, ybuf, out);
    }
}